// Round 10
// baseline (4837.099 us; speedup 1.0000x reference)
//
#include <hip/hip_runtime.h>
#include <hip/hip_bf16.h>
#include <stdint.h>

// LSTM T=512 B=64 F=256 H=1024 CLASSES=1000 — persistent kernel, 256 WGs.
// Round 10: bulk-sentinel dataflow (fix of r9's serialized retry drains).
//   - 4 rotating h buffers, NaN-poison sentinel, fire-and-forget sc1 publish
//     (no flags, no fences, no producer ack wait)
//   - consumer: issue ALL 32 sc1 loads speculatively right after publish,
//     x-MFMA under their flight, ONE vmcnt(0) drain, then BULK retry rounds
//     (re-issue every stale chunk, one drain per round — parallel across all)
//   - dual accumulators halve the dependent MFMA chain
//   - epilogue/cell/publish addressing: r8-verbatim (proven)

typedef __bf16 bf16;
typedef __bf16 bf16x8 __attribute__((ext_vector_type(8)));
typedef __bf16 bf16x4 __attribute__((ext_vector_type(4)));
typedef float  f32x4  __attribute__((ext_vector_type(4)));
typedef unsigned long long u64;
typedef u64 u64x2 __attribute__((ext_vector_type(2)));

#define NWG     256
#define TSTEPS  512
#define BATCH   64
#define FEAT    256
#define HID     1024
#define KTOT    1280
#define WPITCH  1288   // +8 bf16 pad -> conflict-free ds_read_b128
#define HSZ     ((size_t)BATCH * HID)       // elems per h buffer (131072 B)
#define POISON  0xFFF1FFF1FFF1FFF1ULL       // 4x bf16 NaN — impossible h value

// d_ws layout
#define WS_X    ((size_t)0)                  // bf16 x [512][64][256]  16,777,216 B
#define WS_W    ((size_t)16777216)           // bf16 Wcomb [4096][1280] 10,485,760 B
#define WS_HB   (WS_W + (size_t)10485760)    // bf16 hbuf[4][64][1024]  524,288 B

__global__ void k_init(uint4* __restrict__ hb) {
  size_t i = (size_t)blockIdx.x * blockDim.x + threadIdx.x;  // 128*256 x 16B = 512KB
  uint4 z = make_uint4(0u, 0u, 0u, 0u);
  uint4 p = make_uint4(0xFFF1FFF1u, 0xFFF1FFF1u, 0xFFF1FFF1u, 0xFFF1FFF1u);
  hb[i] = (i < 8192) ? z : p;   // buf0 = h_0 = zeros; buf1..3 = poison
}

__global__ void k_conv_x(const float* __restrict__ x, bf16* __restrict__ xb) {
  size_t i = ((size_t)blockIdx.x * blockDim.x + threadIdx.x) * 4;
  float4 v = *(const float4*)(x + i);
  bf16x4 o = { (bf16)v.x, (bf16)v.y, (bf16)v.z, (bf16)v.w };
  *(bf16x4*)(xb + i) = o;
}

__global__ void k_build_w(const float* __restrict__ Wih, const float* __restrict__ Whh,
                          bf16* __restrict__ Wc) {
  int r = blockIdx.x;
  int k4;
  const float* src;
  if (blockIdx.y == 0) {
    k4 = threadIdx.x * 4;
    src = Whh + (size_t)r * HID + k4;
  } else {
    if (threadIdx.x >= 64) return;
    k4 = 1024 + threadIdx.x * 4;
    src = Wih + (size_t)r * FEAT + threadIdx.x * 4;
  }
  float4 v = *(const float4*)src;
  bf16x4 o = { (bf16)v.x, (bf16)v.y, (bf16)v.z, (bf16)v.w };
  *(bf16x4*)(Wc + (size_t)r * KTOT + k4) = o;
}

__device__ __forceinline__ float sigm(float x) { return 1.f / (1.f + __expf(-x)); }
__device__ __forceinline__ float tanh_fast(float x) { return 2.f / (1.f + __expf(-2.f * x)) - 1.f; }

__device__ __forceinline__ void llc_store(void* p, u64 v) {
  __hip_atomic_store((u64*)p, v, __ATOMIC_RELAXED, __HIP_MEMORY_SCOPE_AGENT);
}

// 16B MALL-fresh load (sc1, coherence-point read)
#define LDH(dst, OFF) \
  asm volatile("global_load_dwordx4 %0, %1, off offset:" OFF " sc1" : "=v"(dst) : "v"(ah))
#define WAITV(N) asm volatile("s_waitcnt vmcnt(" #N ")" ::: "memory")
#define SB() __builtin_amdgcn_sched_barrier(0)
#define MFMA0(av, kc) acc0 = __builtin_amdgcn_mfma_f32_16x16x32_bf16( \
    (av), *(const bf16x8*)(brow + (kc) * 32), acc0, 0, 0, 0)
#define MFMAB(av, kc) acc1 = __builtin_amdgcn_mfma_f32_16x16x32_bf16( \
    (av), *(const bf16x8*)(brow + (kc) * 32), acc1, 0, 0, 0)

#define STALE(x) ({ u64x2 _w = __builtin_bit_cast(u64x2, (x)); \
                    (_w[0] == POISON) || (_w[1] == POISON); })
#define RE(r, o) if (STALE(r)) { LDH(r, o); _n = 1; }

__global__ __launch_bounds__(256, 1) void k_lstm(
    const float* __restrict__ bih, const float* __restrict__ bhh,
    const bf16* __restrict__ xb, const bf16* __restrict__ Wc,
    bf16* __restrict__ hbuf)
{
  __shared__ bf16  Wl[32 * WPITCH];   // 82,432 B
  __shared__ float gl[32][33];        // gates staging, +1 pad col
  __shared__ bf16  hstage[32][8];

  const int tid = threadIdx.x;
  const int wg  = blockIdx.x;
  const int ib  = wg & 1;      // batch half (32 rows)
  const int j   = wg >> 1;     // h block (8 h-cols), 0..127

  // ---- load weight slice into LDS
  {
    const int n = tid >> 3;                       // 0..31
    const int g = n >> 3, u = n & 7;
    const bf16* srow = Wc + (size_t)(g * 1024 + j * 8 + u) * KTOT;
    bf16* drow = Wl + n * WPITCH;
    const int c0 = (tid & 7) * 8;
#pragma unroll
    for (int it = 0; it < 20; ++it) {
      int e = c0 + it * 64;
      *(bf16x8*)(drow + e) = *(const bf16x8*)(srow + e);
    }
  }

  const int lane = tid & 63;
  const int wv   = tid >> 6;         // 4 waves
  const int mt   = wv & 1;           // M-tile (16 batches)
  const int nt   = wv >> 1;          // N-tile (16 gate cols)
  const int ln   = lane & 15;
  const int hg   = lane >> 4;        // 0..3

  float bias_r;                      // per-lane: bias of gate col (nt*16+ln)
  {
    int nl = nt * 16 + ln;
    int g = nl >> 3, u = nl & 7;
    int r = g * 1024 + j * 8 + u;
    bias_r = bih[r] + bhh[r];
  }

  const int eb = tid & 31, eu = tid >> 5;   // epilogue ownership: (batch eb, hcol eu)
  float c_st = 0.f;                         // cell state, fp32 in register

  const int bg = ib * 32 + mt * 16 + ln;    // global batch row for A fragment
  const bf16* brow = Wl + (nt * 16 + ln) * WPITCH + hg * 8;

  __syncthreads();

  for (int t = 0; t < TSTEPS; ++t) {
    const bf16* hc = hbuf + (size_t)(t & 3) * HSZ;         // h_t (read)
    bf16*       hn = hbuf + (size_t)((t + 1) & 3) * HSZ;   // h_{t+1} (write)
    bf16*       hz = hbuf + (size_t)((t + 3) & 3) * HSZ;   // poison target

    f32x4 acc0 = {0.f, 0.f, 0.f, 0.f};
    f32x4 acc1 = {0.f, 0.f, 0.f, 0.f};

    const bf16* ah = hc + (size_t)bg * HID + hg * 8;   // 64B-stride fragments

    // ---- speculatively issue ALL 32 h loads (producers are publishing now)
    bf16x8 a0, a1, a2, a3, a4, a5, a6, a7;
    bf16x8 b0, b1, b2, b3, b4, b5, b6, b7;
    bf16x8 c0, c1, c2, c3, c4, c5, c6, c7;
    bf16x8 d0, d1, d2, d3, d4, d5, d6, d7;
    LDH(a0, "0");    LDH(a1, "64");   LDH(a2, "128");  LDH(a3, "192");
    LDH(a4, "256");  LDH(a5, "320");  LDH(a6, "384");  LDH(a7, "448");
    LDH(b0, "512");  LDH(b1, "576");  LDH(b2, "640");  LDH(b3, "704");
    LDH(b4, "768");  LDH(b5, "832");  LDH(b6, "896");  LDH(b7, "960");
    LDH(c0, "1024"); LDH(c1, "1088"); LDH(c2, "1152"); LDH(c3, "1216");
    LDH(c4, "1280"); LDH(c5, "1344"); LDH(c6, "1408"); LDH(c7, "1472");
    LDH(d0, "1536"); LDH(d1, "1600"); LDH(d2, "1664"); LDH(d3, "1728");
    LDH(d4, "1792"); LDH(d5, "1856"); LDH(d6, "1920"); LDH(d7, "1984");

    // ---- x-projection under the loads' flight (xb immutable, L2-cached)
    const bf16* ax = xb + (size_t)t * (BATCH * FEAT) + (size_t)bg * FEAT + hg * 8;
#pragma unroll
    for (int kc = 0; kc < 8; ++kc) {        // x part: K = 1024..1279
      bf16x8 a = *(const bf16x8*)(ax + kc * 32);
      bf16x8 b = *(const bf16x8*)(brow + 1024 + kc * 32);
      acc0 = __builtin_amdgcn_mfma_f32_16x16x32_bf16(a, b, acc0, 0, 0, 0);
    }

    // ---- one drain, then bulk sentinel-retry (one RTT per round, all chunks)
    WAITV(0); SB();
    for (;;) {
      int _n = 0;
      RE(a0, "0");    RE(a1, "64");   RE(a2, "128");  RE(a3, "192");
      RE(a4, "256");  RE(a5, "320");  RE(a6, "384");  RE(a7, "448");
      RE(b0, "512");  RE(b1, "576");  RE(b2, "640");  RE(b3, "704");
      RE(b4, "768");  RE(b5, "832");  RE(b6, "896");  RE(b7, "960");
      RE(c0, "1024"); RE(c1, "1088"); RE(c2, "1152"); RE(c3, "1216");
      RE(c4, "1280"); RE(c5, "1344"); RE(c6, "1408"); RE(c7, "1472");
      RE(d0, "1536"); RE(d1, "1600"); RE(d2, "1664"); RE(d3, "1728");
      RE(d4, "1792"); RE(d5, "1856"); RE(d6, "1920"); RE(d7, "1984");
      if (!_n) break;
      WAITV(0); SB();
    }

    // ---- h-part MFMAs: two independent chains (acc0: a,c; acc1: b,d)
    MFMA0(a0, 0);  MFMAB(b0, 8);  MFMA0(a1, 1);  MFMAB(b1, 9);
    MFMA0(a2, 2);  MFMAB(b2, 10); MFMA0(a3, 3);  MFMAB(b3, 11);
    MFMA0(a4, 4);  MFMAB(b4, 12); MFMA0(a5, 5);  MFMAB(b5, 13);
    MFMA0(a6, 6);  MFMAB(b6, 14); MFMA0(a7, 7);  MFMAB(b7, 15);
    MFMA0(c0, 16); MFMAB(d0, 24); MFMA0(c1, 17); MFMAB(d1, 25);
    MFMA0(c2, 18); MFMAB(d2, 26); MFMA0(c3, 19); MFMAB(d3, 27);
    MFMA0(c4, 20); MFMAB(d4, 28); MFMA0(c5, 21); MFMAB(d5, 29);
    MFMA0(c6, 22); MFMAB(d6, 30); MFMA0(c7, 23); MFMAB(d7, 31);

    // C/D layout (verified): col = lane&15, row = (lane>>4)*4 + reg
#pragma unroll
    for (int r = 0; r < 4; ++r)
      gl[mt * 16 + hg * 4 + r][nt * 16 + ln] = acc0[r] + acc1[r] + bias_r;
    __syncthreads();

    // ---- LSTM cell (each thread owns one (batch, hcol))
    float gi = gl[eb][ 0 + eu];
    float gf = gl[eb][ 8 + eu];
    float gc = gl[eb][16 + eu];
    float go = gl[eb][24 + eu];
    gi = sigm(gi); gf = sigm(gf); go = sigm(go); gc = tanh_fast(gc);
    c_st = gf * c_st + gi * gc;
    hstage[eb][eu] = (bf16)(go * tanh_fast(c_st));
    __syncthreads();

    // ---- publish h tile (fire-and-forget sc1) + poison the t+3 buffer
    if (wv == 0) {
      const u64* hp = (const u64*)&hstage[0][0];   // u64 idx = row*2+half = tid
      const size_t roff = (size_t)(ib * 32 + (tid >> 1)) * HID + j * 8;
      llc_store((u64*)(hn + roff) + (tid & 1), hp[tid]);
      llc_store((u64*)(hz + roff) + (tid & 1), POISON);
    }
  }
}

// out[b][c] = sum_k h_last[b][k] * Wfc[c][k]   (h_512 lands in buf0)
__global__ __launch_bounds__(256) void k_fc(const bf16* __restrict__ h,
                                            const float* __restrict__ Wfc,
                                            float* __restrict__ out) {
  const int tid = threadIdx.x;
  const int ci = tid & 3, b = tid >> 2;
  const int c = blockIdx.x * 4 + ci;
  const bf16*  hr = h   + (size_t)b * HID;
  const float* wr = Wfc + (size_t)c * HID;
  float acc = 0.f;
#pragma unroll 4
  for (int k8 = 0; k8 < 128; ++k8) {
    bf16x8 hv = *(const bf16x8*)(hr + k8 * 8);
    f32x4  w0 = *(const f32x4*)(wr + k8 * 8);
    f32x4  w1 = *(const f32x4*)(wr + k8 * 8 + 4);
    acc += (float)hv[0] * w0[0] + (float)hv[1] * w0[1] + (float)hv[2] * w0[2] + (float)hv[3] * w0[3]
         + (float)hv[4] * w1[0] + (float)hv[5] * w1[1] + (float)hv[6] * w1[2] + (float)hv[7] * w1[3];
  }
  out[(size_t)b * 1000 + c] = acc;
}

extern "C" void kernel_launch(void* const* d_in, const int* in_sizes, int n_in,
                              void* d_out, int out_size, void* d_ws, size_t ws_size,
                              hipStream_t stream) {
  (void)in_sizes; (void)n_in; (void)out_size; (void)ws_size;
  const float* x   = (const float*)d_in[0];
  const float* Wih = (const float*)d_in[1];
  const float* Whh = (const float*)d_in[2];
  const float* bih = (const float*)d_in[3];
  const float* bhh = (const float*)d_in[4];
  const float* Wfc = (const float*)d_in[5];
  char* ws = (char*)d_ws;
  bf16* xb   = (bf16*)(ws + WS_X);
  bf16* Wc   = (bf16*)(ws + WS_W);
  bf16* hbuf = (bf16*)(ws + WS_HB);

  hipLaunchKernelGGL(k_init,    dim3(128),     dim3(256), 0, stream, (uint4*)hbuf);
  hipLaunchKernelGGL(k_conv_x,  dim3(8192),    dim3(256), 0, stream, x, xb);
  hipLaunchKernelGGL(k_build_w, dim3(4096, 2), dim3(256), 0, stream, Wih, Whh, Wc);
  hipLaunchKernelGGL(k_lstm,    dim3(NWG),     dim3(256), 0, stream, bih, bhh, xb, Wc, hbuf);
  hipLaunchKernelGGL(k_fc,      dim3(250),     dim3(256), 0, stream, hbuf, Wfc, (float*)d_out);
}

// Round 11
// 3015.640 us; speedup vs baseline: 1.6040x; 1.6040x over previous
//
#include <hip/hip_runtime.h>
#include <hip/hip_bf16.h>
#include <stdint.h>

// LSTM T=512 B=64 F=256 H=1024 CLASSES=1000 — persistent kernel, 256 WGs.
// Round 11 = round 8 (proven best, 3.07ms) + three safe cuts:
//   - per-wave independent flag polling (2 flags/lane, all waves) and NO
//     syncthreads between poll and h-loads (wave skew decoupled)
//   - dual accumulators (dependent MFMA chain 40 -> 24)
//   - barriers per step: 3 -> 2
// Publish path (64-lane u64 atomicExch + vmcnt(0) + flag exch): r8-verbatim.

typedef __bf16 bf16;
typedef __bf16 bf16x8 __attribute__((ext_vector_type(8)));
typedef __bf16 bf16x4 __attribute__((ext_vector_type(4)));
typedef float  f32x4  __attribute__((ext_vector_type(4)));
typedef unsigned long long u64;

#define NWG     256
#define TSTEPS  512
#define BATCH   64
#define FEAT    256
#define HID     1024
#define KTOT    1280
#define WPITCH  1288   // +8 bf16 pad -> conflict-free ds_read_b128

// d_ws layout
#define WS_X    ((size_t)0)                  // bf16 x [512][64][256]  16,777,216 B
#define WS_W    ((size_t)16777216)           // bf16 Wcomb [4096][1280] 10,485,760 B
#define WS_H0   (WS_W + (size_t)10485760)    // bf16 h0 [64][1024]  131,072 B
#define WS_H1   (WS_H0 + (size_t)131072)     // bf16 h1
#define WS_FLG  (WS_H1 + (size_t)131072)     // 256 flags, 64B stride = 16,384 B

__global__ void k_zero(uint4* __restrict__ p) {
  size_t i = (size_t)blockIdx.x * blockDim.x + threadIdx.x;  // 68*256*16B = 278,528 B
  p[i] = make_uint4(0u, 0u, 0u, 0u);
}

__global__ void k_conv_x(const float* __restrict__ x, bf16* __restrict__ xb) {
  size_t i = ((size_t)blockIdx.x * blockDim.x + threadIdx.x) * 4;
  float4 v = *(const float4*)(x + i);
  bf16x4 o = { (bf16)v.x, (bf16)v.y, (bf16)v.z, (bf16)v.w };
  *(bf16x4*)(xb + i) = o;
}

__global__ void k_build_w(const float* __restrict__ Wih, const float* __restrict__ Whh,
                          bf16* __restrict__ Wc) {
  int r = blockIdx.x;
  int k4;
  const float* src;
  if (blockIdx.y == 0) {
    k4 = threadIdx.x * 4;
    src = Whh + (size_t)r * HID + k4;
  } else {
    if (threadIdx.x >= 64) return;
    k4 = 1024 + threadIdx.x * 4;
    src = Wih + (size_t)r * FEAT + threadIdx.x * 4;
  }
  float4 v = *(const float4*)src;
  bf16x4 o = { (bf16)v.x, (bf16)v.y, (bf16)v.z, (bf16)v.w };
  *(bf16x4*)(Wc + (size_t)r * KTOT + k4) = o;
}

__device__ __forceinline__ float sigm(float x) { return 1.f / (1.f + __expf(-x)); }
__device__ __forceinline__ float tanh_fast(float x) { return 2.f / (1.f + __expf(-2.f * x)) - 1.f; }

// 16B MALL-fresh load (sc1, coherence-point read)
#define LDH(dst, OFF) \
  asm volatile("global_load_dwordx4 %0, %1, off offset:" OFF " sc1" : "=v"(dst) : "v"(ah))
#define WAITV(N) asm volatile("s_waitcnt vmcnt(" #N ")" ::: "memory")
#define SB() __builtin_amdgcn_sched_barrier(0)
#define MFMA0(av, kc) acc0 = __builtin_amdgcn_mfma_f32_16x16x32_bf16( \
    (av), *(const bf16x8*)(brow + (kc) * 32), acc0, 0, 0, 0)
#define MFMAB(av, kc) acc1 = __builtin_amdgcn_mfma_f32_16x16x32_bf16( \
    (av), *(const bf16x8*)(brow + (kc) * 32), acc1, 0, 0, 0)

__global__ __launch_bounds__(256, 1) void k_lstm(
    const float* __restrict__ bih, const float* __restrict__ bhh,
    const bf16* __restrict__ xb, const bf16* __restrict__ Wc,
    bf16* __restrict__ h0, bf16* __restrict__ h1, unsigned* __restrict__ flags)
{
  __shared__ bf16  Wl[32 * WPITCH];   // 82,432 B
  __shared__ float gl[32][33];        // gates staging, +1 pad col
  __shared__ bf16  hstage[32][8];

  const int tid = threadIdx.x;
  const int wg  = blockIdx.x;
  const int ib  = wg & 1;      // batch half (32 rows)
  const int j   = wg >> 1;     // h block (8 h-cols), 0..127

  // ---- load weight slice into LDS (rows n = g*8+u -> global row g*1024 + j*8 + u)
  {
    const int n = tid >> 3;                       // 0..31
    const int g = n >> 3, u = n & 7;
    const bf16* srow = Wc + (size_t)(g * 1024 + j * 8 + u) * KTOT;
    bf16* drow = Wl + n * WPITCH;
    const int c0 = (tid & 7) * 8;
#pragma unroll
    for (int it = 0; it < 20; ++it) {
      int e = c0 + it * 64;                       // covers 0..1279
      *(bf16x8*)(drow + e) = *(const bf16x8*)(srow + e);
    }
  }

  const int lane = tid & 63;
  const int wv   = tid >> 6;         // 4 waves
  const int mt   = wv & 1;           // M-tile (16 batches)
  const int nt   = wv >> 1;          // N-tile (16 gate cols)
  const int ln   = lane & 15;
  const int hg   = lane >> 4;        // 0..3

  float bias_r;                      // per-lane: bias of gate col (nt*16+ln)
  {
    int nl = nt * 16 + ln;
    int g = nl >> 3, u = nl & 7;
    int r = g * 1024 + j * 8 + u;
    bias_r = bih[r] + bhh[r];
  }

  const int eb = tid & 31, eu = tid >> 5;   // epilogue ownership: (batch eb, hcol eu)
  float c_st = 0.f;                         // cell state, fp32 in register

  const int bg = ib * 32 + mt * 16 + ln;    // global batch row for A fragment
  const bf16* brow = Wl + (nt * 16 + ln) * WPITCH + hg * 8;

  // per-wave poll set: every wave covers all 128 same-half flags, 2 per lane
  unsigned* pf0 = flags + (size_t)((2 * lane)     * 2 + ib) * 16;
  unsigned* pf1 = flags + (size_t)((2 * lane + 1) * 2 + ib) * 16;
  unsigned* ownflag = flags + (size_t)wg * 16;

  __syncthreads();

  for (int t = 0; t < TSTEPS; ++t) {
    const bf16* hc = (t & 1) ? h1 : h0;     // read h_{t-1}
    bf16*       hn = (t & 1) ? h0 : h1;     // write h_t

    f32x4 acc0 = {0.f, 0.f, 0.f, 0.f};
    f32x4 acc1 = {0.f, 0.f, 0.f, 0.f};

    // ---- x-projection (xb immutable) — runs while producers still publishing
    const bf16* ax = xb + (size_t)t * (BATCH * FEAT) + (size_t)bg * FEAT + hg * 8;
#pragma unroll
    for (int kc = 0; kc < 8; ++kc) {        // x part: K = 1024..1279
      bf16x8 a = *(const bf16x8*)(ax + kc * 32);
      bf16x8 b = *(const bf16x8*)(brow + 1024 + kc * 32);
      acc0 = __builtin_amdgcn_mfma_f32_16x16x32_bf16(a, b, acc0, 0, 0, 0);
    }

    // ---- per-wave flag wait (no cross-wave barrier: fast waves proceed)
    if (t) {
      const unsigned tt = (unsigned)t;
      for (;;) {
        unsigned f0 = __hip_atomic_load(pf0, __ATOMIC_RELAXED, __HIP_MEMORY_SCOPE_AGENT);
        unsigned f1 = __hip_atomic_load(pf1, __ATOMIC_RELAXED, __HIP_MEMORY_SCOPE_AGENT);
        if (f0 >= tt && f1 >= tt) break;
        __builtin_amdgcn_s_sleep(2);
      }
    }

    // ---- h part: 32x 16B sc1 loads, 4x8 batches, counted vmcnt pipeline
    const bf16* ah = hc + (size_t)bg * HID + hg * 8;   // 64B-stride fragments
    {
      bf16x8 a0, a1, a2, a3, a4, a5, a6, a7;
      bf16x8 c0, c1, c2, c3, c4, c5, c6, c7;
      LDH(a0, "0");    LDH(a1, "64");   LDH(a2, "128");  LDH(a3, "192");
      LDH(a4, "256");  LDH(a5, "320");  LDH(a6, "384");  LDH(a7, "448");
      LDH(c0, "512");  LDH(c1, "576");  LDH(c2, "640");  LDH(c3, "704");
      LDH(c4, "768");  LDH(c5, "832");  LDH(c6, "896");  LDH(c7, "960");
      WAITV(8); SB();
      MFMA0(a0, 0); MFMA0(a1, 1); MFMA0(a2, 2); MFMA0(a3, 3);
      MFMA0(a4, 4); MFMA0(a5, 5); MFMA0(a6, 6); MFMA0(a7, 7);
      LDH(a0, "1024"); LDH(a1, "1088"); LDH(a2, "1152"); LDH(a3, "1216");
      LDH(a4, "1280"); LDH(a5, "1344"); LDH(a6, "1408"); LDH(a7, "1472");
      WAITV(8); SB();
      MFMAB(c0, 8);  MFMAB(c1, 9);  MFMAB(c2, 10); MFMAB(c3, 11);
      MFMAB(c4, 12); MFMAB(c5, 13); MFMAB(c6, 14); MFMAB(c7, 15);
      LDH(c0, "1536"); LDH(c1, "1600"); LDH(c2, "1664"); LDH(c3, "1728");
      LDH(c4, "1792"); LDH(c5, "1856"); LDH(c6, "1920"); LDH(c7, "1984");
      WAITV(8); SB();
      MFMA0(a0, 16); MFMA0(a1, 17); MFMA0(a2, 18); MFMA0(a3, 19);
      MFMA0(a4, 20); MFMA0(a5, 21); MFMA0(a6, 22); MFMA0(a7, 23);
      WAITV(0); SB();
      MFMAB(c0, 24); MFMAB(c1, 25); MFMAB(c2, 26); MFMAB(c3, 27);
      MFMAB(c4, 28); MFMAB(c5, 29); MFMAB(c6, 30); MFMAB(c7, 31);
    }

    // C/D layout (verified): col = lane&15, row = (lane>>4)*4 + reg
#pragma unroll
    for (int r = 0; r < 4; ++r)
      gl[mt * 16 + hg * 4 + r][nt * 16 + ln] = acc0[r] + acc1[r] + bias_r;
    __syncthreads();                       // S2: gl complete (also fences gl reuse)

    // ---- LSTM cell (each thread owns one (batch, hcol))
    float gi = gl[eb][ 0 + eu];
    float gf = gl[eb][ 8 + eu];
    float gc = gl[eb][16 + eu];
    float go = gl[eb][24 + eu];
    gi = sigm(gi); gf = sigm(gf); go = sigm(go); gc = tanh_fast(gc);
    c_st = gf * c_st + gi * gc;
    hstage[eb][eu] = (bf16)(go * tanh_fast(c_st));
    __syncthreads();                       // S3: hstage complete

    // ---- publish h tile: wave 0, 64 lanes x 1 u64 atomicExch, then flag
    if (wv == 0) {
      const u64* hp = (const u64*)&hstage[0][0];          // u64 idx = row*2+half = tid
      u64* dst = (u64*)(hn + (size_t)(ib * 32 + (tid >> 1)) * HID + j * 8) + (tid & 1);
      u64 d0 = __hip_atomic_exchange(dst, hp[tid], __ATOMIC_RELAXED, __HIP_MEMORY_SCOPE_AGENT);
      asm volatile("" :: "v"(d0));                        // keep return live
      asm volatile("s_waitcnt vmcnt(0)" ::: "memory");    // h committed at MALL
      if (tid == 0)
        atomicExch(ownflag, (unsigned)(t + 1));
    }
  }
}

// out[b][c] = sum_k h_last[b][k] * Wfc[c][k]   (131 MFLOP, L2-resident)
__global__ __launch_bounds__(256) void k_fc(const bf16* __restrict__ h,
                                            const float* __restrict__ Wfc,
                                            float* __restrict__ out) {
  const int tid = threadIdx.x;
  const int ci = tid & 3, b = tid >> 2;
  const int c = blockIdx.x * 4 + ci;
  const bf16*  hr = h   + (size_t)b * HID;
  const float* wr = Wfc + (size_t)c * HID;
  float acc = 0.f;
#pragma unroll 4
  for (int k8 = 0; k8 < 128; ++k8) {
    bf16x8 hv = *(const bf16x8*)(hr + k8 * 8);
    f32x4  w0 = *(const f32x4*)(wr + k8 * 8);
    f32x4  w1 = *(const f32x4*)(wr + k8 * 8 + 4);
    acc += (float)hv[0] * w0[0] + (float)hv[1] * w0[1] + (float)hv[2] * w0[2] + (float)hv[3] * w0[3]
         + (float)hv[4] * w1[0] + (float)hv[5] * w1[1] + (float)hv[6] * w1[2] + (float)hv[7] * w1[3];
  }
  out[(size_t)b * 1000 + c] = acc;
}

extern "C" void kernel_launch(void* const* d_in, const int* in_sizes, int n_in,
                              void* d_out, int out_size, void* d_ws, size_t ws_size,
                              hipStream_t stream) {
  (void)in_sizes; (void)n_in; (void)out_size; (void)ws_size;
  const float* x   = (const float*)d_in[0];
  const float* Wih = (const float*)d_in[1];
  const float* Whh = (const float*)d_in[2];
  const float* bih = (const float*)d_in[3];
  const float* bhh = (const float*)d_in[4];
  const float* Wfc = (const float*)d_in[5];
  char* ws = (char*)d_ws;
  bf16* xb = (bf16*)(ws + WS_X);
  bf16* Wc = (bf16*)(ws + WS_W);
  bf16* h0 = (bf16*)(ws + WS_H0);
  bf16* h1 = (bf16*)(ws + WS_H1);
  unsigned* flags = (unsigned*)(ws + WS_FLG);

  hipLaunchKernelGGL(k_zero,    dim3(68),      dim3(256), 0, stream, (uint4*)(ws + WS_H0));
  hipLaunchKernelGGL(k_conv_x,  dim3(8192),    dim3(256), 0, stream, x, xb);
  hipLaunchKernelGGL(k_build_w, dim3(4096, 2), dim3(256), 0, stream, Wih, Whh, Wc);
  hipLaunchKernelGGL(k_lstm,    dim3(NWG),     dim3(256), 0, stream, bih, bhh, xb, Wc, h0, h1, flags);
  hipLaunchKernelGGL(k_fc,      dim3(250),     dim3(256), 0, stream, h0, Wfc, (float*)d_out);
}